// Round 1
// baseline (418.647 us; speedup 1.0000x reference)
//
#include <hip/hip_runtime.h>

typedef __attribute__((ext_vector_type(8))) short short8;
typedef __attribute__((ext_vector_type(4))) float floatx4;

#define LOG2E 1.44269504088896340736f

// fp32 -> bf16 round-to-nearest-even (bit trick; NaN irrelevant here)
__device__ __forceinline__ unsigned short f2bf(float f) {
  unsigned u = __float_as_uint(f);
  u += 0x7FFFu + ((u >> 16) & 1u);
  return (unsigned short)(u >> 16);
}

// swizzled LDS state index (ushort units): XOR row into k bits 3..5
// -> 16 lanes reading same k-slot of 16 different rows spread over 8 16B slots (2-way = free)
__device__ __forceinline__ int sidx(int row, int k) {
  return row * 256 + (k ^ ((row & 7) << 3));
}

__global__ __launch_bounds__(512, 2) void tlstm_kernel(
    const float* __restrict__ x, const float* __restrict__ tim,
    const float* __restrict__ Wi, const float* __restrict__ bi,
    const float* __restrict__ Wh, const float* __restrict__ bh,
    float* __restrict__ out)
{
  __shared__ __align__(16) unsigned short S[16 * 256]; // bf16 state, rows = [h0,c0,h1,c1,...]
  __shared__ float WM[8 * 257];                        // (1 - wt) per (local batch, t); 257 = bank-spread pad

  const int tid = threadIdx.x;
  const int wv  = tid >> 6;        // wave 0..7, owns cols [wv*32, wv*32+32)
  const int l   = tid & 63;
  const int q   = l >> 4;          // k-group / row-group
  const int r   = l & 15;          // A-row / D-col within tile
  const int b0  = blockIdx.x * 8;  // global batch base (8 rows per block)

  const int colA = wv * 32 + r;
  const int colB = colA + 16;

  // ---- one-time: weight fragments into registers (B-operand layout, k = q*8+j) ----
  short8 whA[8], whB[8];
#pragma unroll
  for (int c = 0; c < 8; ++c) {
#pragma unroll
    for (int j = 0; j < 8; ++j) {
      int k = c * 32 + q * 8 + j;
      whA[c][j] = (short)f2bf(Wh[k * 256 + colA]);
      whB[c][j] = (short)f2bf(Wh[k * 256 + colB]);
    }
  }
  short8 wiA[4], wiB[4];
#pragma unroll
  for (int c = 0; c < 4; ++c) {
#pragma unroll
    for (int j = 0; j < 8; ++j) {
      int k = c * 32 + q * 8 + j;
      wiA[c][j] = (short)f2bf(Wi[k * 256 + colA]);
      wiB[c][j] = (short)f2bf(Wi[k * 256 + colB]);
    }
  }
  const float bhA = bh[colA], bhB = bh[colB];
  const float biA = bi[colA], biB = bi[colB];

  // ---- one-time: zero state, precompute wm = 1 - 1/log(dt + 2.7193) ----
  for (int i = tid; i < 16 * 256; i += 512) S[i] = 0;
  for (int i = tid; i < 2048; i += 512) {
    int bl = i >> 8, t = i & 255;
    float v = 0.f;
    if (t < 255) {
      float t0 = tim[(b0 + bl) * 256 + t];
      float t1 = tim[(b0 + bl) * 256 + t + 1];
      v = 1.f - 1.f / logf(t1 - t0 + 2.7193f);
    }
    WM[bl * 257 + t] = v;
  }
  __syncthreads();

  // ---- x prefetch: even A-rows carry x[batch r/2]; odd rows are zero ----
  const int  xr = r >> 1;
  const bool xl = ((r & 1) == 0);
  const float* xbase = x + (long)(b0 + xr) * 32768 + q * 8; // [b][s][128]

  floatx4 xb[8];
  if (xl) {
#pragma unroll
    for (int c = 0; c < 4; ++c) {
      xb[2 * c]     = *(const floatx4*)(xbase + c * 32);
      xb[2 * c + 1] = *(const floatx4*)(xbase + c * 32 + 4);
    }
  }

  float cA0 = 0.f, cA1 = 0.f, cB0 = 0.f, cB1 = 0.f;   // c state, fp32, lane-resident
  float hA0 = 0.f, hA1 = 0.f, hB0 = 0.f, hB1 = 0.f;
  float gA0 = 0.f, gA1 = 0.f, gB0 = 0.f, gB1 = 0.f;

  const short8 zer = {0, 0, 0, 0, 0, 0, 0, 0};

  for (int t = 0; t < 255; ++t) {
    // convert current x to bf16 A-frags
    short8 xf[4];
    if (xl) {
#pragma unroll
      for (int c = 0; c < 4; ++c) {
#pragma unroll
        for (int j = 0; j < 4; ++j) {
          xf[c][j]     = (short)f2bf(xb[2 * c][j]);
          xf[c][4 + j] = (short)f2bf(xb[2 * c + 1][j]);
        }
      }
    } else {
#pragma unroll
      for (int c = 0; c < 4; ++c) xf[c] = zer;
    }
    // prefetch next step's x (HBM latency hides under MFMA + elementwise)
    if (xl && t < 254) {
      const float* xp = xbase + (long)(t + 1) * 128;
#pragma unroll
      for (int c = 0; c < 4; ++c) {
        xb[2 * c]     = *(const floatx4*)(xp + c * 32);
        xb[2 * c + 1] = *(const floatx4*)(xp + c * 32 + 4);
      }
    }
    // state A-frags from LDS (swizzled, 8 x ds_read_b128)
    short8 sf[8];
#pragma unroll
    for (int c = 0; c < 8; ++c)
      sf[c] = *(const short8*)&S[sidx(r, c * 32 + q * 8)];

    // acc init with biases: h-rows get bh+bi, c-rows get bh
    floatx4 accA = {bhA + biA, bhA, bhA + biA, bhA};
    floatx4 accB = {bhB + biB, bhB, bhB + biB, bhB};
#pragma unroll
    for (int c = 0; c < 4; ++c) {
      accA = __builtin_amdgcn_mfma_f32_16x16x32_bf16(xf[c], wiA[c], accA, 0, 0, 0);
      accB = __builtin_amdgcn_mfma_f32_16x16x32_bf16(xf[c], wiB[c], accB, 0, 0, 0);
    }
#pragma unroll
    for (int c = 0; c < 8; ++c) {
      accA = __builtin_amdgcn_mfma_f32_16x16x32_bf16(sf[c], whA[c], accA, 0, 0, 0);
      accB = __builtin_amdgcn_mfma_f32_16x16x32_bf16(sf[c], whB[c], accB, 0, 0, 0);
    }
    __syncthreads();  // all A-frag reads done before S is overwritten

    const float wm0 = WM[(2 * q) * 257 + t];
    const float wm1 = WM[(2 * q + 1) * 257 + t];

    auto proc = [&](float z, float cp, float cin, float wmv,
                    float& cno, float& gno, float& hno, int row, int col) {
      z  = fminf(fmaxf(z, -44.f), 44.f);   // keep u*u finite
      cp = fminf(fmaxf(cp, -44.f), 44.f);
      float u  = __builtin_amdgcn_exp2f(-LOG2E * z);          // e^{-z}
      float g  = __builtin_amdgcn_rcpf(1.f + u);              // sigmoid(z)
      float u2 = u * u;
      float Cb = (1.f - u2) * __builtin_amdgcn_rcpf(1.f + u2); // tanh(z)
      float v  = __builtin_amdgcn_exp2f(-2.f * LOG2E * cp);   // e^{-2 cpre}
      float Cs = (1.f - v) * __builtin_amdgcn_rcpf(1.f + v);  // tanh(cpre)
      float Cstar = fmaf(-Cs, wmv, cin);                      // c - Cs*(1-wt)
      float cn = g * (Cstar + Cb);
      float tv = __builtin_amdgcn_exp2f(-2.f * LOG2E * Cb);
      float T  = (1.f - tv) * __builtin_amdgcn_rcpf(1.f + tv); // tanh(Cb)
      float hn = g * T;
      S[sidx(row, col)]     = f2bf(hn);
      S[sidx(row + 1, col)] = f2bf(cn);
      cno = cn; gno = g; hno = hn;
    };
    proc(accA[0], accA[1], cA0, wm0, cA0, gA0, hA0, 4 * q,     colA);
    proc(accA[2], accA[3], cA1, wm1, cA1, gA1, hA1, 4 * q + 2, colA);
    proc(accB[0], accB[1], cB0, wm0, cB0, gB0, hB0, 4 * q,     colB);
    proc(accB[2], accB[3], cB1, wm1, cB1, gB1, hB1, 4 * q + 2, colB);
    __syncthreads();  // writes visible before next iter's reads
  }

  // ---- epilogue: res = g_last @ Wh + bh (g in h-slots, zeros in c-slots) ----
  S[sidx(4 * q,     colA)] = f2bf(gA0);  S[sidx(4 * q + 1, colA)] = 0;
  S[sidx(4 * q + 2, colA)] = f2bf(gA1);  S[sidx(4 * q + 3, colA)] = 0;
  S[sidx(4 * q,     colB)] = f2bf(gB0);  S[sidx(4 * q + 1, colB)] = 0;
  S[sidx(4 * q + 2, colB)] = f2bf(gB1);  S[sidx(4 * q + 3, colB)] = 0;
  __syncthreads();

  short8 gf[8];
#pragma unroll
  for (int c = 0; c < 8; ++c)
    gf[c] = *(const short8*)&S[sidx(r, c * 32 + q * 8)];
  floatx4 resA = {bhA, bhA, bhA, bhA};
  floatx4 resB = {bhB, bhB, bhB, bhB};
#pragma unroll
  for (int c = 0; c < 8; ++c) {
    resA = __builtin_amdgcn_mfma_f32_16x16x32_bf16(gf[c], whA[c], resA, 0, 0, 0);
    resB = __builtin_amdgcn_mfma_f32_16x16x32_bf16(gf[c], whB[c], resB, 0, 0, 0);
  }

  const long P  = 2048L * 256;
  const long o0 = (long)(b0 + 2 * q) * 256;
  const long o1 = (long)(b0 + 2 * q + 1) * 256;
  out[o0 + colA]         = resA[0];  out[o1 + colA]         = resA[2];
  out[o0 + colB]         = resB[0];  out[o1 + colB]         = resB[2];
  out[P + o0 + colA]     = hA0;      out[P + o1 + colA]     = hA1;
  out[P + o0 + colB]     = hB0;      out[P + o1 + colB]     = hB1;
  out[2 * P + o0 + colA] = cA0;      out[2 * P + o1 + colA] = cA1;
  out[2 * P + o0 + colB] = cB0;      out[2 * P + o1 + colB] = cB1;
}

extern "C" void kernel_launch(void* const* d_in, const int* in_sizes, int n_in,
                              void* d_out, int out_size, void* d_ws, size_t ws_size,
                              hipStream_t stream) {
  const float* xin = (const float*)d_in[0];
  const float* tim = (const float*)d_in[1];
  const float* Wi  = (const float*)d_in[2];
  const float* bi  = (const float*)d_in[3];
  const float* Wh  = (const float*)d_in[4];
  const float* bh  = (const float*)d_in[5];
  tlstm_kernel<<<dim3(256), dim3(512), 0, stream>>>(xin, tim, Wi, bi, Wh, bh, (float*)d_out);
}

// Round 2
// 312.262 us; speedup vs baseline: 1.3407x; 1.3407x over previous
//
#include <hip/hip_runtime.h>

typedef __attribute__((ext_vector_type(8))) short short8;
typedef __attribute__((ext_vector_type(4))) float floatx4;

#define LOG2E 1.44269504088896340736f

union U8 { short8 s; unsigned u[4]; };

// one-time RNE fp32->bf16 (weights)
__device__ __forceinline__ unsigned short f2bf(float f) {
  unsigned u = __float_as_uint(f);
  u += 0x7FFFu + ((u >> 16) & 1u);
  return (unsigned short)(u >> 16);
}

// pack two fp32 -> one u32 of two bf16 (round-half-up), 3 VALU ops
__device__ __forceinline__ unsigned bfpack(float lo, float hi) {
  unsigned a = __float_as_uint(lo) + 0x8000u;
  unsigned b = __float_as_uint(hi) + 0x8000u;
  return __builtin_amdgcn_perm(b, a, 0x07060302u); // [b.hi16 | a.hi16]
}

// swizzled LDS state index (ushort units): XOR row bits into k bits 3..5
__device__ __forceinline__ int sidx(int row, int k) {
  return row * 256 + (k ^ ((row & 7) << 3));
}

__global__ __launch_bounds__(512, 2) void tlstm_kernel(
    const float* __restrict__ x, const float* __restrict__ tim,
    const float* __restrict__ Wi, const float* __restrict__ bi,
    const float* __restrict__ Wh, const float* __restrict__ bh,
    float* __restrict__ out)
{
  // double-buffered bf16 state, rows = [h0,c0,h1,c1,...]
  __shared__ __align__(16) unsigned short S0[16 * 256];
  __shared__ __align__(16) unsigned short S1[16 * 256];
  __shared__ float WM[8 * 257];  // (1 - wt) per (local batch, t)

  const int tid = threadIdx.x;
  const int wv  = tid >> 6;
  const int l   = tid & 63;
  const int q   = l >> 4;
  const int r   = l & 15;
  const int b0  = blockIdx.x * 8;

  const int colA = wv * 32 + r;
  const int colB = colA + 16;

  // ---- weights into registers (B-operand layout, k = c*32 + q*8 + j) ----
  short8 whA[8], whB[8];
#pragma unroll
  for (int c = 0; c < 8; ++c) {
#pragma unroll
    for (int j = 0; j < 8; ++j) {
      int k = c * 32 + q * 8 + j;
      whA[c][j] = (short)f2bf(Wh[k * 256 + colA]);
      whB[c][j] = (short)f2bf(Wh[k * 256 + colB]);
    }
  }
  short8 wiA[4], wiB[4];
#pragma unroll
  for (int c = 0; c < 4; ++c) {
#pragma unroll
    for (int j = 0; j < 8; ++j) {
      int k = c * 32 + q * 8 + j;
      wiA[c][j] = (short)f2bf(Wi[k * 256 + colA]);
      wiB[c][j] = (short)f2bf(Wi[k * 256 + colB]);
    }
  }
  const float bhA = bh[colA], bhB = bh[colB];
  const float bbA = bhA + bi[colA], bbB = bhB + bi[colB];

  // ---- one-time init: zero S0, precompute wm = 1 - 1/log(dt + 2.7193) ----
  for (int i = tid; i < 16 * 256; i += 512) S0[i] = 0;
  for (int i = tid; i < 2048; i += 512) {
    int bl = i >> 8, t = i & 255;
    float v = 0.f;
    if (t < 255) {
      float t0 = tim[(b0 + bl) * 256 + t];
      float t1 = tim[(b0 + bl) * 256 + t + 1];
      v = 1.f - 1.f / logf(t1 - t0 + 2.7193f);
    }
    WM[bl * 257 + t] = v;
  }
  __syncthreads();

  // ---- x addressing: A-row r carries (batch r>>1, step-parity r&1) ----
  const float* xbase = x + (long)(b0 + (r >> 1)) * 32768 + (r & 1) * 128 + q * 8;

  floatx4 xb[8];  // 32 floats = this pair's x fragment data
#pragma unroll
  for (int c = 0; c < 4; ++c) {
    xb[2 * c]     = *(const floatx4*)(xbase + c * 32);
    xb[2 * c + 1] = *(const floatx4*)(xbase + c * 32 + 4);
  }

  float cA0 = 0.f, cA1 = 0.f, cB0 = 0.f, cB1 = 0.f;
  float hA0 = 0.f, hA1 = 0.f, hB0 = 0.f, hB1 = 0.f;
  float gA0 = 0.f, gA1 = 0.f, gB0 = 0.f, gB1 = 0.f;

  auto proc = [&](float z, float cp, float cin, float wmv,
                  float& cno, float& gno, float& hno,
                  int row, int col, unsigned short* Sw) {
    z  = fminf(fmaxf(z, -44.f), 44.f);
    cp = fminf(fmaxf(cp, -44.f), 44.f);
    float u  = __builtin_amdgcn_exp2f(-LOG2E * z);            // e^{-z}
    float g  = __builtin_amdgcn_rcpf(1.f + u);                // sigmoid(z)
    float u2 = u * u;
    float Cb = fmaf(2.f, __builtin_amdgcn_rcpf(1.f + u2), -1.f); // tanh(z)
    float v  = __builtin_amdgcn_exp2f(-2.f * LOG2E * cp);
    float Cs = fmaf(2.f, __builtin_amdgcn_rcpf(1.f + v), -1.f);  // tanh(cpre)
    float Cstar = fmaf(-Cs, wmv, cin);                        // c - Cs*(1-wt)
    float cn = g * (Cstar + Cb);
    float tv = __builtin_amdgcn_exp2f(-2.f * LOG2E * Cb);
    float T  = fmaf(2.f, __builtin_amdgcn_rcpf(1.f + tv), -1.f); // tanh(Cb)
    float hn = g * T;
    Sw[sidx(row, col)]     = (unsigned short)((__float_as_uint(hn) + 0x8000u) >> 16);
    Sw[sidx(row + 1, col)] = (unsigned short)((__float_as_uint(cn) + 0x8000u) >> 16);
    cno = cn; gno = g; hno = hn;
  };

  for (int t2 = 0; t2 < 255; t2 += 2) {
    // pack this pair's x to bf16 frags (add + perm)
    U8 xf[4];
#pragma unroll
    for (int c = 0; c < 4; ++c) {
      xf[c].u[0] = bfpack(xb[2 * c][0],     xb[2 * c][1]);
      xf[c].u[1] = bfpack(xb[2 * c][2],     xb[2 * c][3]);
      xf[c].u[2] = bfpack(xb[2 * c + 1][0], xb[2 * c + 1][1]);
      xf[c].u[3] = bfpack(xb[2 * c + 1][2], xb[2 * c + 1][3]);
    }
    // prefetch next pair
    if (t2 + 2 < 255) {
      const float* xp = xbase + (long)(t2 + 2) * 128;
#pragma unroll
      for (int c = 0; c < 4; ++c) {
        xb[2 * c]     = *(const floatx4*)(xp + c * 32);
        xb[2 * c + 1] = *(const floatx4*)(xp + c * 32 + 4);
      }
    }
    // x-projection for BOTH steps of the pair (rows: even=t2, odd=t2+1)
    floatx4 xaccA = {bbA, bbA, bbA, bbA};
    floatx4 xaccB = {bbB, bbB, bbB, bbB};
#pragma unroll
    for (int c = 0; c < 4; ++c) {
      xaccA = __builtin_amdgcn_mfma_f32_16x16x32_bf16(xf[c].s, wiA[c], xaccA, 0, 0, 0);
      xaccB = __builtin_amdgcn_mfma_f32_16x16x32_bf16(xf[c].s, wiB[c], xaccB, 0, 0, 0);
    }

    // ===== step A (t = t2): read S0, write S1 =====
    {
      short8 sf[8];
#pragma unroll
      for (int c = 0; c < 8; ++c)
        sf[c] = *(const short8*)&S0[sidx(r, c * 32 + q * 8)];
      floatx4 accA = {xaccA[0], bhA, xaccA[2], bhA};
      floatx4 accB = {xaccB[0], bhB, xaccB[2], bhB};
#pragma unroll
      for (int c = 0; c < 8; ++c) {
        accA = __builtin_amdgcn_mfma_f32_16x16x32_bf16(sf[c], whA[c], accA, 0, 0, 0);
        accB = __builtin_amdgcn_mfma_f32_16x16x32_bf16(sf[c], whB[c], accB, 0, 0, 0);
      }
      const float wm0 = WM[(2 * q) * 257 + t2];
      const float wm1 = WM[(2 * q + 1) * 257 + t2];
      proc(accA[0], accA[1], cA0, wm0, cA0, gA0, hA0, 4 * q,     colA, S1);
      proc(accA[2], accA[3], cA1, wm1, cA1, gA1, hA1, 4 * q + 2, colA, S1);
      proc(accB[0], accB[1], cB0, wm0, cB0, gB0, hB0, 4 * q,     colB, S1);
      proc(accB[2], accB[3], cB1, wm1, cB1, gB1, hB1, 4 * q + 2, colB, S1);
      __syncthreads();
    }

    // ===== step B (t = t2+1): read S1, write S0 =====
    if (t2 + 1 < 255) {
      short8 sf[8];
#pragma unroll
      for (int c = 0; c < 8; ++c)
        sf[c] = *(const short8*)&S1[sidx(r, c * 32 + q * 8)];
      floatx4 accA = {xaccA[1], bhA, xaccA[3], bhA};
      floatx4 accB = {xaccB[1], bhB, xaccB[3], bhB};
#pragma unroll
      for (int c = 0; c < 8; ++c) {
        accA = __builtin_amdgcn_mfma_f32_16x16x32_bf16(sf[c], whA[c], accA, 0, 0, 0);
        accB = __builtin_amdgcn_mfma_f32_16x16x32_bf16(sf[c], whB[c], accB, 0, 0, 0);
      }
      const float wm0 = WM[(2 * q) * 257 + t2 + 1];
      const float wm1 = WM[(2 * q + 1) * 257 + t2 + 1];
      proc(accA[0], accA[1], cA0, wm0, cA0, gA0, hA0, 4 * q,     colA, S0);
      proc(accA[2], accA[3], cA1, wm1, cA1, gA1, hA1, 4 * q + 2, colA, S0);
      proc(accB[0], accB[1], cB0, wm0, cB0, gB0, hB0, 4 * q,     colB, S0);
      proc(accB[2], accB[3], cB1, wm1, cB1, gB1, hB1, 4 * q + 2, colB, S0);
      __syncthreads();
    }
  }

  // ---- epilogue: res = g_last @ Wh + bh. Final state lives in S1. ----
  S1[sidx(4 * q,     colA)] = f2bf(gA0);  S1[sidx(4 * q + 1, colA)] = 0;
  S1[sidx(4 * q + 2, colA)] = f2bf(gA1);  S1[sidx(4 * q + 3, colA)] = 0;
  S1[sidx(4 * q,     colB)] = f2bf(gB0);  S1[sidx(4 * q + 1, colB)] = 0;
  S1[sidx(4 * q + 2, colB)] = f2bf(gB1);  S1[sidx(4 * q + 3, colB)] = 0;
  __syncthreads();

  short8 gf[8];
#pragma unroll
  for (int c = 0; c < 8; ++c)
    gf[c] = *(const short8*)&S1[sidx(r, c * 32 + q * 8)];
  floatx4 resA = {bhA, bhA, bhA, bhA};
  floatx4 resB = {bhB, bhB, bhB, bhB};
#pragma unroll
  for (int c = 0; c < 8; ++c) {
    resA = __builtin_amdgcn_mfma_f32_16x16x32_bf16(gf[c], whA[c], resA, 0, 0, 0);
    resB = __builtin_amdgcn_mfma_f32_16x16x32_bf16(gf[c], whB[c], resB, 0, 0, 0);
  }

  const long P  = 2048L * 256;
  const long o0 = (long)(b0 + 2 * q) * 256;
  const long o1 = (long)(b0 + 2 * q + 1) * 256;
  out[o0 + colA]         = resA[0];  out[o1 + colA]         = resA[2];
  out[o0 + colB]         = resB[0];  out[o1 + colB]         = resB[2];
  out[P + o0 + colA]     = hA0;      out[P + o1 + colA]     = hA1;
  out[P + o0 + colB]     = hB0;      out[P + o1 + colB]     = hB1;
  out[2 * P + o0 + colA] = cA0;      out[2 * P + o1 + colA] = cA1;
  out[2 * P + o0 + colB] = cB0;      out[2 * P + o1 + colB] = cB1;
}

extern "C" void kernel_launch(void* const* d_in, const int* in_sizes, int n_in,
                              void* d_out, int out_size, void* d_ws, size_t ws_size,
                              hipStream_t stream) {
  const float* xin = (const float*)d_in[0];
  const float* tim = (const float*)d_in[1];
  const float* Wi  = (const float*)d_in[2];
  const float* bi  = (const float*)d_in[3];
  const float* Wh  = (const float*)d_in[4];
  const float* bh  = (const float*)d_in[5];
  tlstm_kernel<<<dim3(256), dim3(512), 0, stream>>>(xin, tim, Wi, bi, Wh, bh, (float*)d_out);
}

// Round 4
// 288.566 us; speedup vs baseline: 1.4508x; 1.0821x over previous
//
#include <hip/hip_runtime.h>

typedef __attribute__((ext_vector_type(8))) short short8;
typedef __attribute__((ext_vector_type(4))) float floatx4;

#define LOG2E 1.44269504088896340736f

union U8 { short8 s; unsigned u[4]; };

// one-time RNE fp32->bf16 (weights)
__device__ __forceinline__ unsigned short f2bf(float f) {
  unsigned u = __float_as_uint(f);
  u += 0x7FFFu + ((u >> 16) & 1u);
  return (unsigned short)(u >> 16);
}

// two fp32 -> packed 2x bf16 in one instruction
__device__ __forceinline__ unsigned cvtpk(float lo, float hi) {
  unsigned r;
  asm("v_cvt_pk_bf16_f32 %0, %1, %2" : "=v"(r) : "v"(lo), "v"(hi));
  return r;
}

// swizzled LDS state index (ushort units): XOR row bits into k bits 3..5
__device__ __forceinline__ int sidx(int row, int k) {
  return row * 256 + (k ^ ((row & 7) << 3));
}

// odd Taylor-13 tanh for |x|<=1 (max err ~1.0e-3 at |x|=1)
__device__ __forceinline__ float tanh_poly(float x) {
  const float C3 = -0.333333333f, C5 = 0.133333333f, C7 = -0.053968254f;
  const float C9 = 0.021869488f, C11 = -0.008863236f, C13 = 0.003592028f;
  float s = x * x;
  float P = C13;
  P = fmaf(P, s, C11);
  P = fmaf(P, s, C9);
  P = fmaf(P, s, C7);
  P = fmaf(P, s, C5);
  P = fmaf(P, s, C3);
  P = fmaf(P, s, 1.0f);
  return x * P;
}

__global__ __launch_bounds__(512, 2) void tlstm_kernel(
    const float* __restrict__ x, const float* __restrict__ tim,
    const float* __restrict__ Wi, const float* __restrict__ bi,
    const float* __restrict__ Wh, const float* __restrict__ bh,
    float* __restrict__ out)
{
  // two 4096-ushort state buffers (toggle = +4096 additive immediate)
  __shared__ __align__(16) unsigned short S[2 * 4096];
  __shared__ float WM[8 * 257];

  const int tid = threadIdx.x;
  const int wv  = tid >> 6;
  const int l   = tid & 63;
  const int q   = l >> 4;
  const int r   = l & 15;
  const int b0  = blockIdx.x * 8;

  const int colA = wv * 32 + r;
  const int colB = colA + 16;
  const int rb   = (r >> 2) & 1;

  // ---- weights into registers in LOGICAL k-block order (lane-uniform pairing:
  //      B-operand permutations must NOT depend on this lane's r — that bit is
  //      the output column, not the A-row; R3's rb-permuted weights were wrong) ----
  short8 whA[8], whB[8];
#pragma unroll
  for (int c = 0; c < 8; ++c) {
#pragma unroll
    for (int j = 0; j < 8; ++j) {
      int k = c * 32 + q * 8 + j;
      whA[c][j] = (short)f2bf(Wh[k * 256 + colA]);
      whB[c][j] = (short)f2bf(Wh[k * 256 + colB]);
    }
  }
  short8 wiA[4], wiB[4];
#pragma unroll
  for (int c = 0; c < 4; ++c) {
#pragma unroll
    for (int j = 0; j < 8; ++j) {
      int k = c * 32 + q * 8 + j;
      wiA[c][j] = (short)f2bf(Wi[k * 256 + colA]);
      wiB[c][j] = (short)f2bf(Wi[k * 256 + colB]);
    }
  }
  const float bhA = bh[colA], bhB = bh[colB];
  const float bbA = bhA + bi[colA], bbB = bhB + bi[colB];

  // loop-invariant swizzled A-frag read addresses (ushort units), logical c:
  //   raddr[c] = sidx(r, c*32 + q*8) = sbase + 32*(c ^ rb)
  const int sbase = r * 256 + ((q * 8) ^ ((r & 3) << 3));
  int raddr[8];
#pragma unroll
  for (int c = 0; c < 8; ++c) raddr[c] = sbase + 32 * (c ^ rb);

  // hoisted write indices
  int wr0 = sidx(4 * q,     colA), wr1 = sidx(4 * q + 1, colA);
  int wr2 = sidx(4 * q + 2, colA), wr3 = sidx(4 * q + 3, colA);
  int wr4 = sidx(4 * q,     colB), wr5 = sidx(4 * q + 1, colB);
  int wr6 = sidx(4 * q + 2, colB), wr7 = sidx(4 * q + 3, colB);

  // ---- one-time init: zero buf0, precompute wm = 1 - 1/log(dt+2.7193) ----
  for (int i = tid; i < 4096; i += 512) S[i] = 0;
  for (int i = tid; i < 2048; i += 512) {
    int bl = i >> 8, t = i & 255;
    float v = 0.f;
    if (t < 255) {
      float t0 = tim[(b0 + bl) * 256 + t];
      float t1 = tim[(b0 + bl) * 256 + t + 1];
      v = 1.f - 1.f / logf(t1 - t0 + 2.7193f);
    }
    WM[bl * 257 + t] = v;
  }
  __syncthreads();

  // ---- x: A-row r carries (batch r>>1, step-parity r&1) ----
  const float* xbase = x + (long)(b0 + (r >> 1)) * 32768 + (r & 1) * 128 + q * 8;

  floatx4 xb[8];
#pragma unroll
  for (int c = 0; c < 4; ++c) {
    xb[2 * c]     = *(const floatx4*)(xbase + c * 32);
    xb[2 * c + 1] = *(const floatx4*)(xbase + c * 32 + 4);
  }

  float cA0 = 0.f, cA1 = 0.f, cB0 = 0.f, cB1 = 0.f;
  float hA0 = 0.f, hA1 = 0.f, hB0 = 0.f, hB1 = 0.f;
  float gA0 = 0.f, gA1 = 0.f, gB0 = 0.f, gB1 = 0.f;

  // gate math: 2x exp2 + 1x rcp per element (combined-reciprocal trick)
  auto proc = [&](float z0, float cp0, float bh_, float cin, float wmv,
                  float& cno, float& gno, float& hno,
                  unsigned short* Sw, int ih, int ic) {
    float z  = fminf(fmaxf(z0, -10.f), 10.f);
    float cp = fminf(fmaxf(cp0 + bh_, -10.f), 10.f);
    float u  = __builtin_amdgcn_exp2f(-LOG2E * z);          // e^{-z}
    float u2 = u * u;
    float v  = __builtin_amdgcn_exp2f(-2.f * LOG2E * cp);   // e^{-2 cp}
    float a1 = 1.f + u, a2 = 1.f + u2, a3 = 1.f + v;
    float p12 = a1 * a2;
    float D   = __builtin_amdgcn_rcpf(p12 * a3);            // 1/(a1*a2*a3)
    float Da3 = D * a3;
    float g   = Da3 * a2;                                   // sigmoid(z)
    float ir2 = Da3 * a1;                                   // 1/(1+u2)
    float ir3 = D * p12;                                    // 1/(1+v)
    float Cb  = fmaf(-u2, ir2, ir2);                        // tanh(z)
    float Cs  = fmaf(-v, ir3, ir3);                         // tanh(cp)
    float Cstar = fmaf(-Cs, wmv, cin);                      // c - Cs*(1-wt)
    float cn = g * (Cstar + Cb);
    float T  = tanh_poly(Cb);                               // tanh(Cb)
    float hn = g * T;
    Sw[ih] = (unsigned short)((__float_as_uint(hn) + 0x8000u) >> 16);
    Sw[ic] = (unsigned short)((__float_as_uint(cn) + 0x8000u) >> 16);
    cno = cn; gno = g; hno = hn;
  };

  for (int t2 = 0; t2 < 255; t2 += 2) {
    // pack this pair's x to bf16 frags
    U8 xf[4];
#pragma unroll
    for (int c = 0; c < 4; ++c) {
      xf[c].u[0] = cvtpk(xb[2 * c][0],     xb[2 * c][1]);
      xf[c].u[1] = cvtpk(xb[2 * c][2],     xb[2 * c][3]);
      xf[c].u[2] = cvtpk(xb[2 * c + 1][0], xb[2 * c + 1][1]);
      xf[c].u[3] = cvtpk(xb[2 * c + 1][2], xb[2 * c + 1][3]);
    }
    // prefetch next pair
    if (t2 + 2 < 255) {
      const float* xp = xbase + (long)(t2 + 2) * 128;
#pragma unroll
      for (int c = 0; c < 4; ++c) {
        xb[2 * c]     = *(const floatx4*)(xp + c * 32);
        xb[2 * c + 1] = *(const floatx4*)(xp + c * 32 + 4);
      }
    }
    // x-projection for both steps (even rows = t2, odd rows = t2+1), + bi + bh
    floatx4 xaccA = {bbA, bbA, bbA, bbA};
    floatx4 xaccB = {bbB, bbB, bbB, bbB};
#pragma unroll
    for (int c = 0; c < 4; ++c) {
      xaccA = __builtin_amdgcn_mfma_f32_16x16x32_bf16(xf[c].s, wiA[c], xaccA, 0, 0, 0);
      xaccB = __builtin_amdgcn_mfma_f32_16x16x32_bf16(xf[c].s, wiB[c], xaccB, 0, 0, 0);
    }

    // ===== step A (t = t2): read buf0, write buf1 =====
    {
      short8 sf[8];
#pragma unroll
      for (int c = 0; c < 8; ++c)
        sf[c] = *(const short8*)&S[raddr[c]];               // buf0
      floatx4 accA = {xaccA[0], 0.f, xaccA[2], 0.f};
      floatx4 accB = {xaccB[0], 0.f, xaccB[2], 0.f};
#pragma unroll
      for (int c = 0; c < 8; ++c) {
        accA = __builtin_amdgcn_mfma_f32_16x16x32_bf16(sf[c], whA[c], accA, 0, 0, 0);
        accB = __builtin_amdgcn_mfma_f32_16x16x32_bf16(sf[c], whB[c], accB, 0, 0, 0);
      }
      const float wm0 = WM[(2 * q) * 257 + t2];
      const float wm1 = WM[(2 * q + 1) * 257 + t2];
      unsigned short* Sw = &S[4096];
      proc(accA[0], accA[1], bhA, cA0, wm0, cA0, gA0, hA0, Sw, wr0, wr1);
      proc(accA[2], accA[3], bhA, cA1, wm1, cA1, gA1, hA1, Sw, wr2, wr3);
      proc(accB[0], accB[1], bhB, cB0, wm0, cB0, gB0, hB0, Sw, wr4, wr5);
      proc(accB[2], accB[3], bhB, cB1, wm1, cB1, gB1, hB1, Sw, wr6, wr7);
      __syncthreads();
    }

    // ===== step B (t = t2+1): read buf1, write buf0 =====
    if (t2 + 1 < 255) {
      short8 sf[8];
#pragma unroll
      for (int c = 0; c < 8; ++c)
        sf[c] = *(const short8*)&S[4096 + raddr[c]];        // buf1 (+8192B imm)
      floatx4 accA = {xaccA[1], 0.f, xaccA[3], 0.f};
      floatx4 accB = {xaccB[1], 0.f, xaccB[3], 0.f};
#pragma unroll
      for (int c = 0; c < 8; ++c) {
        accA = __builtin_amdgcn_mfma_f32_16x16x32_bf16(sf[c], whA[c], accA, 0, 0, 0);
        accB = __builtin_amdgcn_mfma_f32_16x16x32_bf16(sf[c], whB[c], accB, 0, 0, 0);
      }
      const float wm0 = WM[(2 * q) * 257 + t2 + 1];
      const float wm1 = WM[(2 * q + 1) * 257 + t2 + 1];
      unsigned short* Sw = &S[0];
      proc(accA[0], accA[1], bhA, cA0, wm0, cA0, gA0, hA0, Sw, wr0, wr1);
      proc(accA[2], accA[3], bhA, cA1, wm1, cA1, gA1, hA1, Sw, wr2, wr3);
      proc(accB[0], accB[1], bhB, cB0, wm0, cB0, gB0, hB0, Sw, wr4, wr5);
      proc(accB[2], accB[3], bhB, cB1, wm1, cB1, gB1, hB1, Sw, wr6, wr7);
      __syncthreads();
    }
  }

  // ---- epilogue: res = g_last @ Wh + bh. Final state in buf1 (t=254 = step A). ----
  {
    unsigned short* Sw = &S[4096];
    Sw[wr0] = f2bf(gA0);  Sw[wr1] = 0;
    Sw[wr2] = f2bf(gA1);  Sw[wr3] = 0;
    Sw[wr4] = f2bf(gB0);  Sw[wr5] = 0;
    Sw[wr6] = f2bf(gB1);  Sw[wr7] = 0;
  }
  __syncthreads();

  short8 gf[8];
#pragma unroll
  for (int c = 0; c < 8; ++c)
    gf[c] = *(const short8*)&S[4096 + raddr[c]];
  floatx4 resA = {bhA, bhA, bhA, bhA};
  floatx4 resB = {bhB, bhB, bhB, bhB};
#pragma unroll
  for (int c = 0; c < 8; ++c) {
    resA = __builtin_amdgcn_mfma_f32_16x16x32_bf16(gf[c], whA[c], resA, 0, 0, 0);
    resB = __builtin_amdgcn_mfma_f32_16x16x32_bf16(gf[c], whB[c], resB, 0, 0, 0);
  }

  const long P  = 2048L * 256;
  const long o0 = (long)(b0 + 2 * q) * 256;
  const long o1 = (long)(b0 + 2 * q + 1) * 256;
  out[o0 + colA]         = resA[0];  out[o1 + colA]         = resA[2];
  out[o0 + colB]         = resB[0];  out[o1 + colB]         = resB[2];
  out[P + o0 + colA]     = hA0;      out[P + o1 + colA]     = hA1;
  out[P + o0 + colB]     = hB0;      out[P + o1 + colB]     = hB1;
  out[2 * P + o0 + colA] = cA0;      out[2 * P + o1 + colA] = cA1;
  out[2 * P + o0 + colB] = cB0;      out[2 * P + o1 + colB] = cB1;
}

extern "C" void kernel_launch(void* const* d_in, const int* in_sizes, int n_in,
                              void* d_out, int out_size, void* d_ws, size_t ws_size,
                              hipStream_t stream) {
  const float* xin = (const float*)d_in[0];
  const float* tim = (const float*)d_in[1];
  const float* Wi  = (const float*)d_in[2];
  const float* bi  = (const float*)d_in[3];
  const float* Wh  = (const float*)d_in[4];
  const float* bh  = (const float*)d_in[5];
  tlstm_kernel<<<dim3(256), dim3(512), 0, stream>>>(xin, tim, Wi, bi, Wh, bh, (float*)d_out);
}

// Round 5
// 272.648 us; speedup vs baseline: 1.5355x; 1.0584x over previous
//
#include <hip/hip_runtime.h>

typedef __attribute__((ext_vector_type(8))) short short8;
typedef __attribute__((ext_vector_type(4))) float floatx4;
typedef __attribute__((ext_vector_type(2))) float floatx2;

#define LOG2E 1.44269504088896340736f

// raw barrier: drains LDS only (all cross-wave deps are via LDS); keeps the
// x-staging global loads in flight across steps (no vmcnt drain).
#define BAR() asm volatile("s_waitcnt lgkmcnt(0)\n\ts_barrier" ::: "memory")

// one-time RNE fp32->bf16 (weights)
__device__ __forceinline__ unsigned short f2bf(float f) {
  unsigned u = __float_as_uint(f);
  u += 0x7FFFu + ((u >> 16) & 1u);
  return (unsigned short)(u >> 16);
}

// two fp32 -> packed 2x bf16 in one instruction
__device__ __forceinline__ unsigned cvtpk(float lo, float hi) {
  unsigned r;
  asm("v_cvt_pk_bf16_f32 %0, %1, %2" : "=v"(r) : "v"(lo), "v"(hi));
  return r;
}

// swizzled LDS state index (ushort units): XOR row bits into k bits 3..5
__device__ __forceinline__ int sidx(int row, int k) {
  return row * 256 + (k ^ ((row & 7) << 3));
}

__global__ __launch_bounds__(1024, 4) void tlstm_kernel(
    const float* __restrict__ x, const float* __restrict__ tim,
    const float* __restrict__ Wi, const float* __restrict__ bi,
    const float* __restrict__ Wh, const float* __restrict__ bh,
    float* __restrict__ out)
{
  // state: 16 rows [h0,c0,...,h7,c7] x 256 cols bf16, double-buffered
  __shared__ __align__(16) unsigned short Sst[2 * 4096];   // 16 KB
  // x-tile: 16 rows (batch, step-parity) x 128 bf16, double-buffered
  __shared__ __align__(16) unsigned short Sx[2 * 2048];    //  8 KB
  // decay weights, transposed: WMt[t*8 + b] = 1 - 1/log(dt + C2)
  __shared__ float WMt[2048];                              //  8 KB

  const int tid = threadIdx.x;
  const int wv  = tid >> 6;          // wave 0..15, owns cols [wv*16, wv*16+16)
  const int l   = tid & 63;
  const int q   = l >> 4;
  const int r   = l & 15;
  const int b0  = blockIdx.x * 8;    // 8 batches per block
  const int col = wv * 16 + r;

  // ---- weights into registers (B-operand, k = c*32 + q*8 + j), one tile ----
  short8 wh[8];
#pragma unroll
  for (int c = 0; c < 8; ++c)
#pragma unroll
    for (int j = 0; j < 8; ++j)
      wh[c][j] = (short)f2bf(Wh[(c * 32 + q * 8 + j) * 256 + col]);
  short8 wi[4];
#pragma unroll
  for (int c = 0; c < 4; ++c)
#pragma unroll
    for (int j = 0; j < 8; ++j)
      wi[c][j] = (short)f2bf(Wi[(c * 32 + q * 8 + j) * 256 + col]);
  const float bhc = bh[col], bic = bi[col];

  // ---- loop-invariant swizzled addresses ----
  // state frag read: addr(c) = r*256 + ((c*32+q*8) ^ ((r&7)<<3))
  //                = Bs + 32*((c&1)^rbx) + 64*(c>>1)
  const int rbx = (r >> 2) & 1;
  const int Bs  = r * 256 + 8 * (q ^ (r & 3));
  const int raE = Bs + 32 * rbx;        // even c
  const int raO = Bs + 32 * (1 - rbx);  // odd  c
  // x frag read (row stride 128): same structure
  const int Bx  = r * 128 + 8 * (q ^ (r & 3));
  const int xaE = Bx + 32 * rbx;
  const int xaO = Bx + 32 * (1 - rbx);
  // state write indices (h,c of batches 2q, 2q+1 at this col)
  const int wr0 = sidx(4 * q,     col), wr1 = sidx(4 * q + 1, col);
  const int wr2 = sidx(4 * q + 2, col), wr3 = sidx(4 * q + 3, col);
  // x staging: wave w stages row w (batch w>>1, parity w&1), lane l -> 2 floats
  const int xwi = wv * 128 + ((2 * l) ^ ((wv & 7) << 3));
  const float* xp = x + (long)(b0 + (wv >> 1)) * 32768 + (wv & 1) * 128 + l * 2;

  // ---- one-time init ----
  *(unsigned long long*)&Sst[tid * 4] = 0ULL;  // zero state buf0 (8 KB)
  for (int i = tid; i < 2040; i += 1024) {
    int t = i >> 3, bl = i & 7;
    float t0 = tim[(b0 + bl) * 256 + t];
    float t1 = tim[(b0 + bl) * 256 + t + 1];
    WMt[i] = 1.f - 1.f / logf(t1 - t0 + 2.7193f);
  }
  {  // stage pair 0 into Sx buf0
    floatx2 v = *(const floatx2*)xp;
    *(unsigned*)&Sx[xwi] = cvtpk(v.x, v.y);
  }
  xp += 256;
  __syncthreads();  // real barrier once (drains prologue)

  float c0 = 0.f, c1 = 0.f, h0 = 0.f, h1 = 0.f, g0 = 0.f, g1 = 0.f;
  int xro = 0;       // x read buffer offset (ushort units): 0 / 2048
  int wmi = 2 * q;   // WMt index for step A of current pair

  // gate math: 2x exp2 + 1x rcp per element (combined-reciprocal, R4-proven)
  auto proc1 = [&](float z0, float cp0, float cin, float wmv,
                   float& cno, float& gno, float& hno, int ih, int ic, int woff) {
    float z  = fminf(fmaxf(z0,  -10.f), 10.f);
    float cp = fminf(fmaxf(cp0, -10.f), 10.f);
    float u  = __builtin_amdgcn_exp2f(-LOG2E * z);
    float u2 = u * u;
    float v  = __builtin_amdgcn_exp2f(-2.f * LOG2E * cp);
    float a1 = 1.f + u, a2 = 1.f + u2, a3 = 1.f + v;
    float p12 = a1 * a2;
    float D   = __builtin_amdgcn_rcpf(p12 * a3);
    float Da3 = D * a3;
    float g   = Da3 * a2;                       // sigmoid(z)
    float ir2 = Da3 * a1;                       // 1/(1+u2)
    float ir3 = D * p12;                        // 1/(1+v)
    float Cb  = fmaf(-u2, ir2, ir2);            // tanh(z)
    float Cs  = fmaf(-v, ir3, ir3);             // tanh(cp)
    float Cstar = fmaf(-Cs, wmv, cin);
    float cn = g * (Cstar + Cb);
    // tanh(Cb) via odd Taylor-13 (|Cb|<=1, err ~1e-3 << bf16 state quantum)
    float s = Cb * Cb;
    float P = fmaf(0.003592028f, s, -0.008863236f);
    P = fmaf(P, s, 0.021869488f);
    P = fmaf(P, s, -0.053968254f);
    P = fmaf(P, s, 0.133333333f);
    P = fmaf(P, s, -0.333333333f);
    P = fmaf(P, s, 1.0f);
    float hn = g * (Cb * P);
    Sst[woff + ih] = (unsigned short)((__float_as_uint(hn) + 0x8000u) >> 16);
    Sst[woff + ic] = (unsigned short)((__float_as_uint(cn) + 0x8000u) >> 16);
    cno = cn; gno = g; hno = hn;
  };

  auto dostep = [&](int roff, int woff, float xz0, float xz1, int wmoff) {
    short8 sf[8];
    sf[0] = *(const short8*)&Sst[roff + raE];
    sf[1] = *(const short8*)&Sst[roff + raO];
    sf[2] = *(const short8*)&Sst[roff + raE + 64];
    sf[3] = *(const short8*)&Sst[roff + raO + 64];
    sf[4] = *(const short8*)&Sst[roff + raE + 128];
    sf[5] = *(const short8*)&Sst[roff + raO + 128];
    sf[6] = *(const short8*)&Sst[roff + raE + 192];
    sf[7] = *(const short8*)&Sst[roff + raO + 192];
    // two independent 4-chains to halve serial MFMA latency
    floatx4 aP = {bhc, bhc, bhc, bhc};
    floatx4 aQ = {0.f, 0.f, 0.f, 0.f};
    aP = __builtin_amdgcn_mfma_f32_16x16x32_bf16(sf[0], wh[0], aP, 0, 0, 0);
    aQ = __builtin_amdgcn_mfma_f32_16x16x32_bf16(sf[1], wh[1], aQ, 0, 0, 0);
    aP = __builtin_amdgcn_mfma_f32_16x16x32_bf16(sf[2], wh[2], aP, 0, 0, 0);
    aQ = __builtin_amdgcn_mfma_f32_16x16x32_bf16(sf[3], wh[3], aQ, 0, 0, 0);
    aP = __builtin_amdgcn_mfma_f32_16x16x32_bf16(sf[4], wh[4], aP, 0, 0, 0);
    aQ = __builtin_amdgcn_mfma_f32_16x16x32_bf16(sf[5], wh[5], aQ, 0, 0, 0);
    aP = __builtin_amdgcn_mfma_f32_16x16x32_bf16(sf[6], wh[6], aP, 0, 0, 0);
    aQ = __builtin_amdgcn_mfma_f32_16x16x32_bf16(sf[7], wh[7], aQ, 0, 0, 0);
    floatx2 wmv = *(const floatx2*)&WMt[wmoff];
    float z0  = aP[0] + aQ[0] + xz0;
    float cp0 = aP[1] + aQ[1];
    float z1  = aP[2] + aQ[2] + xz1;
    float cp1 = aP[3] + aQ[3];
    proc1(z0, cp0, c0, wmv.x, c0, g0, h0, wr0, wr1, woff);
    proc1(z1, cp1, c1, wmv.y, c1, g1, h1, wr2, wr3, woff);
    BAR();
  };

  floatx4 xacc;
  auto loadx = [&]() {  // x-projection for both steps of the pair (+bi)
    short8 xf[4];
    xf[0] = *(const short8*)&Sx[xro + xaE];
    xf[1] = *(const short8*)&Sx[xro + xaO];
    xf[2] = *(const short8*)&Sx[xro + xaE + 64];
    xf[3] = *(const short8*)&Sx[xro + xaO + 64];
    floatx4 a = {bic, bic, bic, bic};
    a = __builtin_amdgcn_mfma_f32_16x16x32_bf16(xf[0], wi[0], a, 0, 0, 0);
    a = __builtin_amdgcn_mfma_f32_16x16x32_bf16(xf[1], wi[1], a, 0, 0, 0);
    a = __builtin_amdgcn_mfma_f32_16x16x32_bf16(xf[2], wi[2], a, 0, 0, 0);
    a = __builtin_amdgcn_mfma_f32_16x16x32_bf16(xf[3], wi[3], a, 0, 0, 0);
    xacc = a;
  };

  for (int p = 0; p < 127; ++p) {
    // issue next pair's x loads early (consumed after step A -> latency hidden)
    floatx2 nv = *(const floatx2*)xp;
    xp += 256;
    loadx();  // current pair's x-proj: slots {b2q:tA, b2q:tB, b2q+1:tA, b2q+1:tB}
    // step A (t even): read buf0, write buf1
    dostep(0, 4096, xacc[0], xacc[2], wmi);
    // finish staging next pair into the other x buffer
    *(unsigned*)&Sx[(xro ^ 2048) + xwi] = cvtpk(nv.x, nv.y);
    // step B (t odd): read buf1, write buf0
    dostep(4096, 0, xacc[1], xacc[3], wmi + 8);
    xro ^= 2048;
    wmi += 16;
  }

  // tail: t = 254 (step A of pair 127; x staged by p=126)
  loadx();
  dostep(0, 4096, xacc[0], xacc[2], wmi);

  // ---- epilogue: res = g_last @ Wh + bh ----
  Sst[wr0] = f2bf(g0);  Sst[wr1] = 0;   // g-tile into buf0 (h-slots=g, c-slots=0)
  Sst[wr2] = f2bf(g1);  Sst[wr3] = 0;
  BAR();
  short8 gf[8];
  gf[0] = *(const short8*)&Sst[raE];
  gf[1] = *(const short8*)&Sst[raO];
  gf[2] = *(const short8*)&Sst[raE + 64];
  gf[3] = *(const short8*)&Sst[raO + 64];
  gf[4] = *(const short8*)&Sst[raE + 128];
  gf[5] = *(const short8*)&Sst[raO + 128];
  gf[6] = *(const short8*)&Sst[raE + 192];
  gf[7] = *(const short8*)&Sst[raO + 192];
  floatx4 res = {bhc, bhc, bhc, bhc};
#pragma unroll
  for (int c = 0; c < 8; ++c)
    res = __builtin_amdgcn_mfma_f32_16x16x32_bf16(gf[c], wh[c], res, 0, 0, 0);

  const long P  = 2048L * 256;
  const long o0 = (long)(b0 + 2 * q) * 256;
  const long o1 = (long)(b0 + 2 * q + 1) * 256;
  out[o0 + col]         = res[0];
  out[o1 + col]         = res[2];
  out[P + o0 + col]     = h0;
  out[P + o1 + col]     = h1;
  out[2 * P + o0 + col] = c0;
  out[2 * P + o1 + col] = c1;
}

extern "C" void kernel_launch(void* const* d_in, const int* in_sizes, int n_in,
                              void* d_out, int out_size, void* d_ws, size_t ws_size,
                              hipStream_t stream) {
  const float* xin = (const float*)d_in[0];
  const float* tim = (const float*)d_in[1];
  const float* Wi  = (const float*)d_in[2];
  const float* bi  = (const float*)d_in[3];
  const float* Wh  = (const float*)d_in[4];
  const float* bh  = (const float*)d_in[5];
  tlstm_kernel<<<dim3(256), dim3(1024), 0, stream>>>(xin, tim, Wi, bi, Wh, bh, (float*)d_out);
}